// Round 2
// baseline (670.674 us; speedup 1.0000x reference)
//
#include <hip/hip_runtime.h>
#include <hip/hip_bf16.h>

#define NDIM 128
#define BDIM 131072
#define NMZI 8128                      // 128*127/2
#define PF   8                         // prefetch depth (power of 2)
#define UROWS (NDIM + 2 * PF)          // 144: pad rows for prefetch overrun
static constexpr float CC = 0.70710678118654752440f;  // sqrt(0.5)

typedef __attribute__((ext_vector_type(8))) short bf16x8;
typedef __attribute__((ext_vector_type(4))) float f32x4;

// Static device scratch — do NOT rely on d_ws (size unknown; suspected crash cause).
__device__ __align__(16) float4         g_ph[NMZI];        // (cos phi, sin phi, C*cos th, C*sin th)
__device__ __align__(8)  float2         g_dt[NDIM];        // output phases (cos, sin)
__device__ __align__(16) unsigned short g_Ur[16 * NDIM * 8];  // bf16 U real, B-fragment layout [kg][n][e]
__device__ __align__(16) unsigned short g_Ui[16 * NDIM * 8];  // bf16 U imag

__device__ inline unsigned short f2bf(float f) {
    union { __hip_bfloat16 h; unsigned short u; } cv;
    cv.h = __float2bfloat16(f);
    return cv.u;
}

// ---------------- K1: phase precompute ----------------
__global__ void phase_prep(const float* __restrict__ mzi,
                           const float* __restrict__ oph) {
    int q = blockIdx.x * blockDim.x + threadIdx.x;
    if (q < NMZI) {
        float th = mzi[2 * q];
        float p  = mzi[2 * q + 1];
        float sp, cp, st, ct;
        sincosf(p,  &sp, &cp);
        sincosf(th, &st, &ct);
        g_ph[q] = make_float4(cp, sp, CC * ct, CC * st);
    } else if (q < NMZI + NDIM) {
        int n = q - NMZI;
        float s, c;
        sincosf(oph[n], &s, &c);
        g_dt[n] = make_float2(c, s);
    }
}

// ---------------- K2: build unitary ----------------
// 4 blocks x 32 threads (single wave per block => no barriers needed).
// Block owns 32 columns of U; 1 thread = 1 column. U rows in LDS; within
// mesh-sweep i, row i stays in registers. 8-deep register prefetch of
// (rj, phase) hides LDS latency; next sweep's phases staged global->reg
// at sweep start, reg->LDS at sweep end (double-buffered).
__global__ __launch_bounds__(32) void build_u() {
    __shared__ float2 Usm[UROWS][32];
    __shared__ float4 phbuf[2][UROWS];
    const int c = threadIdx.x;              // local column 0..31
    const int col = blockIdx.x * 32 + c;    // global column (= k index)

    // init: U0 = I (plus zeroed pad rows), zero phase buffers
    for (int n = 0; n < UROWS; ++n) Usm[n][c] = make_float2(0.f, 0.f);
    Usm[col][c] = make_float2(1.f, 0.f);
    for (int t = c; t < UROWS; t += 32) {
        phbuf[0][t] = make_float4(0.f, 0.f, 0.f, 0.f);
        phbuf[1][t] = make_float4(0.f, 0.f, 0.f, 0.f);
    }
    // stage sweep 0 phases (cnt = 127)
    for (int t = c; t < NDIM - 1; t += 32) phbuf[0][t] = g_ph[t];

    int base = 0;
    for (int i = 0; i < NDIM - 1; ++i) {
        const int cnt = NDIM - 1 - i;
        const int cur = i & 1, nxt = cur ^ 1;

        // issue next sweep's phase loads into registers (complete during inner loop)
        float4 stg[4];
        const int nn = cnt - 1;             // next sweep's count (0 on last sweep)
        const int bnext = base + cnt;
        #pragma unroll
        for (int u = 0; u < 4; ++u) {
            int t = c + u * 32;
            if (t < nn) stg[u] = g_ph[bnext + t];
        }

        float2 ri = Usm[i][c];
        float2 rjb[PF]; float4 qb[PF];
        #pragma unroll
        for (int u = 0; u < PF; ++u) {
            rjb[u] = Usm[i + 1 + u][c];
            qb[u]  = phbuf[cur][u];
        }
        const int cntp = (cnt + PF - 1) & ~(PF - 1);
        for (int jj = 0; jj < cntp; jj += PF) {
            #pragma unroll
            for (int u = 0; u < PF; ++u) {
                const int j = jj + u;
                float4 q  = qb[u];
                float2 rj = rjb[u];
                // prefetch slot for step j+PF (pad rows/entries if OOB; discarded)
                rjb[u] = Usm[i + 1 + j + PF][c];
                qb[u]  = phbuf[cur][j + PF];
                // t = e_phi * rj
                float tr = fmaf(q.x, rj.x, -q.y * rj.y);
                float ti = fmaf(q.x, rj.y,  q.y * rj.x);
                // new_j = C*e_th*(ri - t)
                float Ar = ri.x - tr;
                float Ai = ri.y - ti;
                float2 nj;
                nj.x = fmaf(q.z, Ar, -q.w * Ai);
                nj.y = fmaf(q.z, Ai,  q.w * Ar);
                if (j < cnt) {              // wave-uniform guard (tail of padded loop)
                    Usm[i + 1 + j][c] = nj;
                    ri.x = CC * (ri.x + tr);
                    ri.y = CC * (ri.y + ti);
                }
            }
        }
        Usm[i][c] = ri;

        // commit staged phases for next sweep
        #pragma unroll
        for (int u = 0; u < 4; ++u) {
            int t = c + u * 32;
            if (t < nn) phbuf[nxt][t] = stg[u];
        }
        base += cnt;
    }

    // epilogue: U[n][m] *= d[n]; emit bf16 in B-fragment layout [kg][n][e], k = col
    const int kg = col >> 3, e = col & 7;
    for (int n = 0; n < NDIM; ++n) {
        float2 u = Usm[n][c];
        float2 d = g_dt[n];
        float vr = u.x * d.x - u.y * d.y;
        float vi = u.x * d.y + u.y * d.x;
        g_Ur[(kg * NDIM + n) * 8 + e] = f2bf(vr);
        g_Ui[(kg * NDIM + n) * 8 + e] = f2bf(vi);
    }
}

// ---------------- K3: out[b,n] = sum_m U[n,m] x[b,m] ----------------
// 2048 blocks x 256 threads (4 waves); wave computes 16 b-rows x 128 n.
// MFMA 16x16x32 bf16: A[row=lane&15][k=(lane>>4)*8+e], B[k][col=lane&15],
// D[row=(lane>>4)*4+reg][col=lane&15].
// OMODE 0: d_out = float32 real part only (out_size == B*N)
// OMODE 1: d_out = bf16 interleaved (re,im) pairs (out_size == 2*B*N)
template <int OMODE>
__global__ __launch_bounds__(256) void cmatmul(const float* __restrict__ xr,
                                               const float* __restrict__ xi,
                                               void* __restrict__ outp) {
    const int lane  = threadIdx.x & 63;
    const int w     = threadIdx.x >> 6;
    const int btile = blockIdx.x * 64 + w * 16;
    const int r15   = lane & 15;
    const int kg4   = lane >> 4;           // 0..3
    const int bload = btile + r15;

    const bf16x8* Ur = (const bf16x8*)g_Ur;
    const bf16x8* Ui = (const bf16x8*)g_Ui;

    const float* xrp = xr + (size_t)bload * NDIM;
    const float* xip = xi + (size_t)bload * NDIM;

    bf16x8 ar[4], ai[4], ain[4];
    #pragma unroll
    for (int kc = 0; kc < 4; ++kc) {
        const int k0 = kc * 32 + kg4 * 8;
        float4 rlo = *(const float4*)(xrp + k0);
        float4 rhi = *(const float4*)(xrp + k0 + 4);
        float4 ilo = *(const float4*)(xip + k0);
        float4 ihi = *(const float4*)(xip + k0 + 4);
        bf16x8 vr, vi, vn;
        vr[0] = (short)f2bf(rlo.x); vr[1] = (short)f2bf(rlo.y);
        vr[2] = (short)f2bf(rlo.z); vr[3] = (short)f2bf(rlo.w);
        vr[4] = (short)f2bf(rhi.x); vr[5] = (short)f2bf(rhi.y);
        vr[6] = (short)f2bf(rhi.z); vr[7] = (short)f2bf(rhi.w);
        vi[0] = (short)f2bf(ilo.x); vi[1] = (short)f2bf(ilo.y);
        vi[2] = (short)f2bf(ilo.z); vi[3] = (short)f2bf(ilo.w);
        vi[4] = (short)f2bf(ihi.x); vi[5] = (short)f2bf(ihi.y);
        vi[6] = (short)f2bf(ihi.z); vi[7] = (short)f2bf(ihi.w);
        #pragma unroll
        for (int e = 0; e < 8; ++e) vn[e] = (short)(vi[e] ^ 0x8000);
        ar[kc] = vr; ai[kc] = vi; ain[kc] = vn;
    }

    #pragma unroll
    for (int nt = 0; nt < 8; ++nt) {
        f32x4 accR = {0.f, 0.f, 0.f, 0.f};
        f32x4 accI = {0.f, 0.f, 0.f, 0.f};
        #pragma unroll
        for (int kc = 0; kc < 4; ++kc) {
            const int kg = kc * 4 + kg4;
            bf16x8 br = Ur[kg * NDIM + nt * 16 + r15];
            bf16x8 bi = Ui[kg * NDIM + nt * 16 + r15];
            accR = __builtin_amdgcn_mfma_f32_16x16x32_bf16(ar[kc],  br, accR, 0, 0, 0);
            accR = __builtin_amdgcn_mfma_f32_16x16x32_bf16(ain[kc], bi, accR, 0, 0, 0);
            accI = __builtin_amdgcn_mfma_f32_16x16x32_bf16(ar[kc],  bi, accI, 0, 0, 0);
            accI = __builtin_amdgcn_mfma_f32_16x16x32_bf16(ai[kc],  br, accI, 0, 0, 0);
        }
        const int n    = nt * 16 + r15;
        const int brow = btile + kg4 * 4;
        if (OMODE == 0) {
            float* o = (float*)outp;
            #pragma unroll
            for (int r = 0; r < 4; ++r)
                o[(size_t)(brow + r) * NDIM + n] = accR[r];
        } else {
            ushort2* o = (ushort2*)outp;
            #pragma unroll
            for (int r = 0; r < 4; ++r)
                o[(size_t)(brow + r) * NDIM + n] = make_ushort2(f2bf(accR[r]), f2bf(accI[r]));
        }
    }
}

extern "C" void kernel_launch(void* const* d_in, const int* in_sizes, int n_in,
                              void* d_out, int out_size, void* d_ws, size_t ws_size,
                              hipStream_t stream) {
    const float* xr  = (const float*)d_in[0];
    const float* xi  = (const float*)d_in[1];
    const float* mzi = (const float*)d_in[2];
    const float* oph = (const float*)d_in[3];

    phase_prep<<<dim3((NMZI + NDIM + 255) / 256), dim3(256), 0, stream>>>(mzi, oph);
    build_u<<<dim3(4), dim3(32), 0, stream>>>();
    if (out_size == BDIM * NDIM) {
        // float32, real part only
        cmatmul<0><<<dim3(BDIM / 64), dim3(256), 0, stream>>>(xr, xi, d_out);
    } else {
        // bf16 interleaved (re, im)
        cmatmul<1><<<dim3(BDIM / 64), dim3(256), 0, stream>>>(xr, xi, d_out);
    }
}

// Round 3
// 163.749 us; speedup vs baseline: 4.0957x; 4.0957x over previous
//
#include <hip/hip_runtime.h>
#include <hip/hip_bf16.h>

#define NDIM 128
#define BDIM 131072
#define NMZI 8128                       // 128*127/2
#define NCHUNK 8
#define CSTEP (NMZI / NCHUNK)           // 1016 steps per chunk
#define PF 8                            // prefetch depth
#define UROWS (NDIM + 2 * PF)           // 144: pad rows for prefetch overrun
#define PHPAD (CSTEP + 2 * PF)          // phase buffer incl. zeroed pad
static constexpr float CC = 0.70710678118654752440f;  // sqrt(0.5)

typedef __attribute__((ext_vector_type(8))) short bf16x8;
typedef __attribute__((ext_vector_type(4))) float f32x4;

// Static device scratch (d_ws size unknown -> don't touch it)
__device__ __align__(16) float4         g_ph[NMZI];          // (cos phi, sin phi, C*cos th, C*sin th)
__device__ __align__(8)  float2         g_dt[NDIM];          // output phases (cos, sin)
__device__ __align__(16) float2         g_V[NCHUNK * NDIM * NDIM];  // chunk partial unitaries
__device__ __align__(16) float2         g_W[4 * NDIM * NDIM];       // compose level 1
__device__ __align__(16) float2         g_Y[2 * NDIM * NDIM];       // compose level 2
__device__ __align__(16) unsigned short g_Ur[16 * NDIM * 8];  // bf16 U real, B-frag layout [kg][n][e]
__device__ __align__(16) unsigned short g_Ui[16 * NDIM * 8];  // bf16 U imag

__device__ inline unsigned short f2bf(float f) {
    union { __hip_bfloat16 h; unsigned short u; } cv;
    cv.h = __float2bfloat16(f);
    return cv.u;
}

// ---------------- K1: phase precompute ----------------
__global__ void phase_prep(const float* __restrict__ mzi,
                           const float* __restrict__ oph) {
    int q = blockIdx.x * blockDim.x + threadIdx.x;
    if (q < NMZI) {
        float th = mzi[2 * q];
        float p  = mzi[2 * q + 1];
        float sp, cp, st, ct;
        sincosf(p,  &sp, &cp);
        sincosf(th, &st, &ct);
        g_ph[q] = make_float4(cp, sp, CC * ct, CC * st);
    } else if (q < NMZI + NDIM) {
        int n = q - NMZI;
        float s, c;
        sincosf(oph[n], &s, &c);
        g_dt[n] = make_float2(c, s);
    }
}

// ---------------- K2: build chunk partial unitaries ----------------
// grid (4 col-groups, NCHUNK chunks) x 32 threads. Each block applies its
// chunk's 1016 consecutive rotations to a 32-column slab of identity.
// Row i of the active sweep lives in registers; 8-deep LDS prefetch of
// (rj, phase); branch-free inner body (cndmask write-back of old rj on
// padded tail steps).
__global__ __launch_bounds__(32) void build_chunks() {
    __shared__ float2 Usm[UROWS][32];
    __shared__ float4 phs[PHPAD];
    const int c     = threadIdx.x;
    const int col   = blockIdx.x * 32 + c;
    const int chunk = blockIdx.y;
    const int s0 = chunk * CSTEP, s1 = s0 + CSTEP;

    for (int n = 0; n < UROWS; ++n) Usm[n][c] = make_float2(0.f, 0.f);
    Usm[col][c] = make_float2(1.f, 0.f);
    for (int t = c; t < CSTEP; t += 32) phs[t] = g_ph[s0 + t];
    if (c < 2 * PF) phs[CSTEP + c] = make_float4(0.f, 0.f, 0.f, 0.f);
    __syncthreads();

    int s = s0, i = 0, base = 0;
    while (base + (NDIM - 1 - i) <= s0) { base += NDIM - 1 - i; ++i; }
    while (s < s1) {
        const int cnt  = NDIM - 1 - i;                 // full sweep length
        const int j0   = (i + 1) + (s - base);         // first row j this segment
        const int segN = min(s1, base + cnt) - s;      // steps this segment
        const int ps   = s - s0;                       // phase cursor

        float2 ri = Usm[i][c];
        float2 rjb[PF]; float4 qb[PF];
        #pragma unroll
        for (int u = 0; u < PF; ++u) {
            rjb[u] = Usm[j0 + u][c];
            qb[u]  = phs[ps + u];
        }
        const int nP = (segN + PF - 1) & ~(PF - 1);
        for (int jj = 0; jj < nP; jj += PF) {
            #pragma unroll
            for (int u = 0; u < PF; ++u) {
                const int t = jj + u;
                const int j = j0 + t;
                const float4 q  = qb[u];
                const float2 rj = rjb[u];
                // prefetch for step t+PF (pad rows / zeroed pad phases if OOB)
                rjb[u] = Usm[j + PF][c];
                qb[u]  = phs[ps + t + PF];
                // t' = e_phi * rj
                const float tr = fmaf(q.x, rj.x, -q.y * rj.y);
                const float ti = fmaf(q.x, rj.y,  q.y * rj.x);
                // new_j = C*e_th*(ri - t')
                const float Ar = ri.x - tr, Ai = ri.y - ti;
                const float njx = fmaf(q.z, Ar, -q.w * Ai);
                const float njy = fmaf(q.z, Ai,  q.w * Ar);
                const bool pr = t < segN;
                Usm[j][c] = make_float2(pr ? njx : rj.x, pr ? njy : rj.y);
                // ri = C*(ri + t')
                const float nrx = CC * (ri.x + tr);
                const float nry = CC * (ri.y + ti);
                ri.x = pr ? nrx : ri.x;
                ri.y = pr ? nry : ri.y;
            }
        }
        Usm[i][c] = ri;
        s += segN; base += cnt; ++i;
    }
    __syncthreads();

    float2* Vp = g_V + chunk * NDIM * NDIM;
    for (int n = 0; n < NDIM; ++n) Vp[n * NDIM + col] = Usm[n][c];
}

// ---------------- K3: compose tree level ----------------
// level 0: W_p = V[2p+1] * V[2p], p=0..3   (g_V -> g_W)
// level 1: Y_q = W[2q+1] * W[2q], q=0..1   (g_W -> g_Y)
// grid (128 rows, nprod), 128 threads (thread = output column m).
__global__ __launch_bounds__(128) void compose(int level) {
    const int p = blockIdx.y, n = blockIdx.x, m = threadIdx.x;
    const float2* A; const float2* B; float2* Cout;
    if (level == 0) {
        A = g_V + (2 * p + 1) * NDIM * NDIM;
        B = g_V + (2 * p) * NDIM * NDIM;
        Cout = g_W + p * NDIM * NDIM;
    } else {
        A = g_W + (2 * p + 1) * NDIM * NDIM;
        B = g_W + (2 * p) * NDIM * NDIM;
        Cout = g_Y + p * NDIM * NDIM;
    }
    __shared__ float2 arow[NDIM];
    arow[m] = A[n * NDIM + m];
    __syncthreads();
    float cr = 0.f, ci = 0.f;
    #pragma unroll 8
    for (int k = 0; k < NDIM; ++k) {
        const float2 b = B[k * NDIM + m];
        const float2 a = arow[k];
        cr = fmaf(a.x, b.x, fmaf(-a.y, b.y, cr));
        ci = fmaf(a.x, b.y, fmaf( a.y, b.x, ci));
    }
    Cout[n * NDIM + m] = make_float2(cr, ci);
}

// ---------------- K4: final compose U = Y1*Y0, apply diag, emit bf16 ----------------
__global__ __launch_bounds__(128) void compose_final() {
    const int n = blockIdx.x, m = threadIdx.x;
    const float2* A = g_Y + NDIM * NDIM;   // Y1 (left)
    const float2* B = g_Y;                 // Y0 (right)
    __shared__ float2 arow[NDIM];
    arow[m] = A[n * NDIM + m];
    __syncthreads();
    float cr = 0.f, ci = 0.f;
    #pragma unroll 8
    for (int k = 0; k < NDIM; ++k) {
        const float2 b = B[k * NDIM + m];
        const float2 a = arow[k];
        cr = fmaf(a.x, b.x, fmaf(-a.y, b.y, cr));
        ci = fmaf(a.x, b.y, fmaf( a.y, b.x, ci));
    }
    const float2 d = g_dt[n];
    const float vr = fmaf(cr, d.x, -ci * d.y);
    const float vi = fmaf(cr, d.y,  ci * d.x);
    const int kg = m >> 3, e = m & 7;
    g_Ur[(kg * NDIM + n) * 8 + e] = f2bf(vr);
    g_Ui[(kg * NDIM + n) * 8 + e] = f2bf(vi);
}

// ---------------- K5: out[b,n] = sum_m U[n,m] x[b,m] ----------------
// 2048 blocks x 256 threads (4 waves); wave computes 16 b-rows x 128 n.
// OMODE 0: d_out = float32 real part only; OMODE 1: bf16 (re,im) pairs.
template <int OMODE>
__global__ __launch_bounds__(256) void cmatmul(const float* __restrict__ xr,
                                               const float* __restrict__ xi,
                                               void* __restrict__ outp) {
    const int lane  = threadIdx.x & 63;
    const int w     = threadIdx.x >> 6;
    const int btile = blockIdx.x * 64 + w * 16;
    const int r15   = lane & 15;
    const int kg4   = lane >> 4;
    const int bload = btile + r15;

    const bf16x8* Ur = (const bf16x8*)g_Ur;
    const bf16x8* Ui = (const bf16x8*)g_Ui;

    const float* xrp = xr + (size_t)bload * NDIM;
    const float* xip = xi + (size_t)bload * NDIM;

    bf16x8 ar[4], ai[4], ain[4];
    #pragma unroll
    for (int kc = 0; kc < 4; ++kc) {
        const int k0 = kc * 32 + kg4 * 8;
        float4 rlo = *(const float4*)(xrp + k0);
        float4 rhi = *(const float4*)(xrp + k0 + 4);
        float4 ilo = *(const float4*)(xip + k0);
        float4 ihi = *(const float4*)(xip + k0 + 4);
        bf16x8 vr, vi, vn;
        vr[0] = (short)f2bf(rlo.x); vr[1] = (short)f2bf(rlo.y);
        vr[2] = (short)f2bf(rlo.z); vr[3] = (short)f2bf(rlo.w);
        vr[4] = (short)f2bf(rhi.x); vr[5] = (short)f2bf(rhi.y);
        vr[6] = (short)f2bf(rhi.z); vr[7] = (short)f2bf(rhi.w);
        vi[0] = (short)f2bf(ilo.x); vi[1] = (short)f2bf(ilo.y);
        vi[2] = (short)f2bf(ilo.z); vi[3] = (short)f2bf(ilo.w);
        vi[4] = (short)f2bf(ihi.x); vi[5] = (short)f2bf(ihi.y);
        vi[6] = (short)f2bf(ihi.z); vi[7] = (short)f2bf(ihi.w);
        #pragma unroll
        for (int e = 0; e < 8; ++e) vn[e] = (short)(vi[e] ^ 0x8000);
        ar[kc] = vr; ai[kc] = vi; ain[kc] = vn;
    }

    #pragma unroll
    for (int nt = 0; nt < 8; ++nt) {
        f32x4 accR = {0.f, 0.f, 0.f, 0.f};
        f32x4 accI = {0.f, 0.f, 0.f, 0.f};
        #pragma unroll
        for (int kc = 0; kc < 4; ++kc) {
            const int kg = kc * 4 + kg4;
            bf16x8 br = Ur[kg * NDIM + nt * 16 + r15];
            bf16x8 bi = Ui[kg * NDIM + nt * 16 + r15];
            accR = __builtin_amdgcn_mfma_f32_16x16x32_bf16(ar[kc],  br, accR, 0, 0, 0);
            accR = __builtin_amdgcn_mfma_f32_16x16x32_bf16(ain[kc], bi, accR, 0, 0, 0);
            accI = __builtin_amdgcn_mfma_f32_16x16x32_bf16(ar[kc],  bi, accI, 0, 0, 0);
            accI = __builtin_amdgcn_mfma_f32_16x16x32_bf16(ai[kc],  br, accI, 0, 0, 0);
        }
        const int n    = nt * 16 + r15;
        const int brow = btile + kg4 * 4;
        if (OMODE == 0) {
            float* o = (float*)outp;
            #pragma unroll
            for (int r = 0; r < 4; ++r)
                o[(size_t)(brow + r) * NDIM + n] = accR[r];
        } else {
            ushort2* o = (ushort2*)outp;
            #pragma unroll
            for (int r = 0; r < 4; ++r)
                o[(size_t)(brow + r) * NDIM + n] = make_ushort2(f2bf(accR[r]), f2bf(accI[r]));
        }
    }
}

extern "C" void kernel_launch(void* const* d_in, const int* in_sizes, int n_in,
                              void* d_out, int out_size, void* d_ws, size_t ws_size,
                              hipStream_t stream) {
    const float* xr  = (const float*)d_in[0];
    const float* xi  = (const float*)d_in[1];
    const float* mzi = (const float*)d_in[2];
    const float* oph = (const float*)d_in[3];

    phase_prep<<<dim3((NMZI + NDIM + 255) / 256), dim3(256), 0, stream>>>(mzi, oph);
    build_chunks<<<dim3(4, NCHUNK), dim3(32), 0, stream>>>();
    compose<<<dim3(NDIM, 4), dim3(128), 0, stream>>>(0);
    compose<<<dim3(NDIM, 2), dim3(128), 0, stream>>>(1);
    compose_final<<<dim3(NDIM), dim3(128), 0, stream>>>();
    if (out_size == BDIM * NDIM) {
        cmatmul<0><<<dim3(BDIM / 64), dim3(256), 0, stream>>>(xr, xi, d_out);
    } else {
        cmatmul<1><<<dim3(BDIM / 64), dim3(256), 0, stream>>>(xr, xi, d_out);
    }
}

// Round 4
// 131.836 us; speedup vs baseline: 5.0872x; 1.2421x over previous
//
#include <hip/hip_runtime.h>
#include <hip/hip_bf16.h>

#define NDIM 128
#define BDIM 131072
#define NMZI 8128                       // 128*127/2
#define NCHUNK 8
#define CSTEP (NMZI / NCHUNK)           // 1016 steps per chunk
#define NJG 8                           // j-groups per block (scan groups)
#define NCOL 32                         // columns per block
#define NLOC 16                         // max local scan length = ceil(127/8)
static constexpr float CC = 0.70710678118654752440f;  // sqrt(0.5)

typedef __attribute__((ext_vector_type(8))) short bf16x8;
typedef __attribute__((ext_vector_type(4))) float f32x4;

// Static device scratch (d_ws size unknown -> don't touch it)
__device__ __align__(16) float4         g_ph[NMZI];          // (cos phi, sin phi, C*cos th, C*sin th)
__device__ __align__(8)  float2         g_dt[NDIM];          // output phases (cos, sin)
__device__ __align__(16) float2         g_V[NCHUNK * NDIM * NDIM];  // chunk partial unitaries
__device__ __align__(16) float2         g_W[4 * NDIM * NDIM];       // compose level 1
__device__ __align__(16) float2         g_Y[2 * NDIM * NDIM];       // compose level 2
__device__ __align__(16) unsigned short g_Ur[16 * NDIM * 8];  // bf16 U real, B-frag layout [kg][n][e]
__device__ __align__(16) unsigned short g_Ui[16 * NDIM * 8];  // bf16 U imag

__device__ inline unsigned short f2bf(float f) {
    union { __hip_bfloat16 h; unsigned short u; } cv;
    cv.h = __float2bfloat16(f);
    return cv.u;
}

// ---------------- K1: phase precompute ----------------
__global__ void phase_prep(const float* __restrict__ mzi,
                           const float* __restrict__ oph) {
    int q = blockIdx.x * blockDim.x + threadIdx.x;
    if (q < NMZI) {
        float th = mzi[2 * q];
        float p  = mzi[2 * q + 1];
        float sp, cp, st, ct;
        sincosf(p,  &sp, &cp);
        sincosf(th, &st, &ct);
        g_ph[q] = make_float4(cp, sp, CC * ct, CC * st);
    } else if (q < NMZI + NDIM) {
        int n = q - NMZI;
        float s, c;
        sincosf(oph[n], &s, &c);
        g_dt[n] = make_float2(c, s);
    }
}

// ---------------- K2: build chunk partial unitaries (affine-scan) ----------------
// grid (4 col-slabs, NCHUNK) x 256 threads = (8 j-groups x 32 columns).
// Within a sweep segment [jA, jA+L): t_j = e_phi*U[j] are independent;
// ri obeys ri_j = C*ri_{j-1} + C*t_j  (affine). Each j-group serially
// composes <=16 elements in registers, cross-group exclusive prefix via
// LDS, then new_j = C*e_th*(ri_{j-1} - t_j) finishes in parallel.
__global__ __launch_bounds__(256) void build_scan() {
    __shared__ float2 Usm[NDIM][NCOL];        // 32 KB: V slab (rows x 32 cols)
    __shared__ float4 phs[CSTEP];             // 16.25 KB: staged phases
    __shared__ float4 comp[NJG][NCOL];        // (A, B.re, B.im, -) per group
    const int tid   = threadIdx.x;
    const int c     = tid & 31;
    const int g     = tid >> 5;
    const int col0  = blockIdx.x * NCOL;
    const int chunk = blockIdx.y;
    const int s0 = chunk * CSTEP, s1 = s0 + CSTEP;

    // V0 = identity slab
    for (int k = g; k < NDIM; k += NJG)
        Usm[k][c] = make_float2((k == col0 + c) ? 1.f : 0.f, 0.f);
    // stage this chunk's phases
    for (int t = tid; t < CSTEP; t += 256) phs[t] = g_ph[s0 + t];
    __syncthreads();

    // locate first sweep of this chunk
    int i = 0, base = 0;
    while (base + (NDIM - 1 - i) <= s0) { base += NDIM - 1 - i; ++i; }

    int s = s0;
    while (s < s1) {
        const int cnt  = NDIM - 1 - i;
        const int jA   = i + 1 + (s - base);          // first row j this segment
        const int L    = min(s1, base + cnt) - s;     // segment length
        const int nloc = (L + NJG - 1) >> 3;          // per-group elements
        const int myBeg = g * nloc;
        const int myN   = max(0, min(nloc, L - myBeg));
        const int pbase = s - s0;                     // phase cursor

        const float2 r0 = Usm[i][c];                  // read BEFORE barrier

        // pass 1: t_j + local affine composite (A, B): r' = A*r + B
        float2 treg[NLOC];
        float2 qth[NLOC];
        float  A = 1.f;
        float2 Bc = make_float2(0.f, 0.f);
        #pragma unroll
        for (int kk = 0; kk < NLOC; ++kk) {
            if (kk < myN) {
                const int off = myBeg + kk;
                const float4 q  = phs[pbase + off];
                const float2 rj = Usm[jA + off][c];
                const float tr = fmaf(q.x, rj.x, -q.y * rj.y);
                const float ti = fmaf(q.x, rj.y,  q.y * rj.x);
                treg[kk] = make_float2(tr, ti);
                qth[kk]  = make_float2(q.z, q.w);
                Bc.x = CC * (Bc.x + tr);
                Bc.y = CC * (Bc.y + ti);
                A *= CC;
            }
        }
        comp[g][c] = make_float4(A, Bc.x, Bc.y, 0.f);
        __syncthreads();

        // exclusive prefix over groups < g, applied to r0
        float2 r = r0;
        for (int h = 0; h < g; ++h) {
            const float4 cm = comp[h][c];
            r.x = fmaf(cm.x, r.x, cm.y);
            r.y = fmaf(cm.x, r.y, cm.z);
        }

        // pass 2: new_j = C*e_th*(ri_{j-1} - t_j); advance r
        #pragma unroll
        for (int kk = 0; kk < NLOC; ++kk) {
            if (kk < myN) {
                const float2 t = treg[kk];
                const float2 q = qth[kk];
                const float dr = r.x - t.x, di = r.y - t.y;
                const float njx = fmaf(q.x, dr, -q.y * di);
                const float njy = fmaf(q.x, di,  q.y * dr);
                Usm[jA + myBeg + kk][c] = make_float2(njx, njy);
                r.x = CC * (r.x + t.x);
                r.y = CC * (r.y + t.y);
            }
        }
        // exactly one group ends at L: writes final ri
        if (myN > 0 && (myBeg + myN == L))
            Usm[i][c] = r;
        __syncthreads();

        s += L;
        if (s == base + cnt) { base += cnt; ++i; }
    }

    float2* Vp = g_V + chunk * NDIM * NDIM;
    for (int k = g; k < NDIM; k += NJG)
        Vp[k * NDIM + col0 + c] = Usm[k][c];
}

// ---------------- K3: compose tree level ----------------
// level 0: W_p = V[2p+1] * V[2p], p=0..3   (g_V -> g_W)
// level 1: Y_q = W[2q+1] * W[2q], q=0..1   (g_W -> g_Y)
__global__ __launch_bounds__(128) void compose(int level) {
    const int p = blockIdx.y, n = blockIdx.x, m = threadIdx.x;
    const float2* A; const float2* B; float2* Cout;
    if (level == 0) {
        A = g_V + (2 * p + 1) * NDIM * NDIM;
        B = g_V + (2 * p) * NDIM * NDIM;
        Cout = g_W + p * NDIM * NDIM;
    } else {
        A = g_W + (2 * p + 1) * NDIM * NDIM;
        B = g_W + (2 * p) * NDIM * NDIM;
        Cout = g_Y + p * NDIM * NDIM;
    }
    __shared__ float2 arow[NDIM];
    arow[m] = A[n * NDIM + m];
    __syncthreads();
    float cr = 0.f, ci = 0.f;
    #pragma unroll 8
    for (int k = 0; k < NDIM; ++k) {
        const float2 b = B[k * NDIM + m];
        const float2 a = arow[k];
        cr = fmaf(a.x, b.x, fmaf(-a.y, b.y, cr));
        ci = fmaf(a.x, b.y, fmaf( a.y, b.x, ci));
    }
    Cout[n * NDIM + m] = make_float2(cr, ci);
}

// ---------------- K4: final compose U = Y1*Y0, apply diag, emit bf16 ----------------
__global__ __launch_bounds__(128) void compose_final() {
    const int n = blockIdx.x, m = threadIdx.x;
    const float2* A = g_Y + NDIM * NDIM;   // Y1 (left)
    const float2* B = g_Y;                 // Y0 (right)
    __shared__ float2 arow[NDIM];
    arow[m] = A[n * NDIM + m];
    __syncthreads();
    float cr = 0.f, ci = 0.f;
    #pragma unroll 8
    for (int k = 0; k < NDIM; ++k) {
        const float2 b = B[k * NDIM + m];
        const float2 a = arow[k];
        cr = fmaf(a.x, b.x, fmaf(-a.y, b.y, cr));
        ci = fmaf(a.x, b.y, fmaf( a.y, b.x, ci));
    }
    const float2 d = g_dt[n];
    const float vr = fmaf(cr, d.x, -ci * d.y);
    const float vi = fmaf(cr, d.y,  ci * d.x);
    const int kg = m >> 3, e = m & 7;
    g_Ur[(kg * NDIM + n) * 8 + e] = f2bf(vr);
    g_Ui[(kg * NDIM + n) * 8 + e] = f2bf(vi);
}

// ---------------- K5: out[b,n] = sum_m U[n,m] x[b,m] ----------------
// OMODE 0: d_out = float32 real part only; OMODE 1: bf16 (re,im) pairs.
template <int OMODE>
__global__ __launch_bounds__(256) void cmatmul(const float* __restrict__ xr,
                                               const float* __restrict__ xi,
                                               void* __restrict__ outp) {
    const int lane  = threadIdx.x & 63;
    const int w     = threadIdx.x >> 6;
    const int btile = blockIdx.x * 64 + w * 16;
    const int r15   = lane & 15;
    const int kg4   = lane >> 4;
    const int bload = btile + r15;

    const bf16x8* Ur = (const bf16x8*)g_Ur;
    const bf16x8* Ui = (const bf16x8*)g_Ui;

    const float* xrp = xr + (size_t)bload * NDIM;
    const float* xip = xi + (size_t)bload * NDIM;

    bf16x8 ar[4], ai[4], ain[4];
    #pragma unroll
    for (int kc = 0; kc < 4; ++kc) {
        const int k0 = kc * 32 + kg4 * 8;
        float4 rlo = *(const float4*)(xrp + k0);
        float4 rhi = *(const float4*)(xrp + k0 + 4);
        float4 ilo = *(const float4*)(xip + k0);
        float4 ihi = *(const float4*)(xip + k0 + 4);
        bf16x8 vr, vi, vn;
        vr[0] = (short)f2bf(rlo.x); vr[1] = (short)f2bf(rlo.y);
        vr[2] = (short)f2bf(rlo.z); vr[3] = (short)f2bf(rlo.w);
        vr[4] = (short)f2bf(rhi.x); vr[5] = (short)f2bf(rhi.y);
        vr[6] = (short)f2bf(rhi.z); vr[7] = (short)f2bf(rhi.w);
        vi[0] = (short)f2bf(ilo.x); vi[1] = (short)f2bf(ilo.y);
        vi[2] = (short)f2bf(ilo.z); vi[3] = (short)f2bf(ilo.w);
        vi[4] = (short)f2bf(ihi.x); vi[5] = (short)f2bf(ihi.y);
        vi[6] = (short)f2bf(ihi.z); vi[7] = (short)f2bf(ihi.w);
        #pragma unroll
        for (int e = 0; e < 8; ++e) vn[e] = (short)(vi[e] ^ 0x8000);
        ar[kc] = vr; ai[kc] = vi; ain[kc] = vn;
    }

    #pragma unroll
    for (int nt = 0; nt < 8; ++nt) {
        f32x4 accR = {0.f, 0.f, 0.f, 0.f};
        f32x4 accI = {0.f, 0.f, 0.f, 0.f};
        #pragma unroll
        for (int kc = 0; kc < 4; ++kc) {
            const int kg = kc * 4 + kg4;
            bf16x8 br = Ur[kg * NDIM + nt * 16 + r15];
            bf16x8 bi = Ui[kg * NDIM + nt * 16 + r15];
            accR = __builtin_amdgcn_mfma_f32_16x16x32_bf16(ar[kc],  br, accR, 0, 0, 0);
            accR = __builtin_amdgcn_mfma_f32_16x16x32_bf16(ain[kc], bi, accR, 0, 0, 0);
            accI = __builtin_amdgcn_mfma_f32_16x16x32_bf16(ar[kc],  bi, accI, 0, 0, 0);
            accI = __builtin_amdgcn_mfma_f32_16x16x32_bf16(ai[kc],  br, accI, 0, 0, 0);
        }
        const int n    = nt * 16 + r15;
        const int brow = btile + kg4 * 4;
        if (OMODE == 0) {
            float* o = (float*)outp;
            #pragma unroll
            for (int r = 0; r < 4; ++r)
                o[(size_t)(brow + r) * NDIM + n] = accR[r];
        } else {
            ushort2* o = (ushort2*)outp;
            #pragma unroll
            for (int r = 0; r < 4; ++r)
                o[(size_t)(brow + r) * NDIM + n] = make_ushort2(f2bf(accR[r]), f2bf(accI[r]));
        }
    }
}

extern "C" void kernel_launch(void* const* d_in, const int* in_sizes, int n_in,
                              void* d_out, int out_size, void* d_ws, size_t ws_size,
                              hipStream_t stream) {
    const float* xr  = (const float*)d_in[0];
    const float* xi  = (const float*)d_in[1];
    const float* mzi = (const float*)d_in[2];
    const float* oph = (const float*)d_in[3];

    phase_prep<<<dim3((NMZI + NDIM + 255) / 256), dim3(256), 0, stream>>>(mzi, oph);
    build_scan<<<dim3(4, NCHUNK), dim3(256), 0, stream>>>();
    compose<<<dim3(NDIM, 4), dim3(128), 0, stream>>>(0);
    compose<<<dim3(NDIM, 2), dim3(128), 0, stream>>>(1);
    compose_final<<<dim3(NDIM), dim3(128), 0, stream>>>();
    if (out_size == BDIM * NDIM) {
        cmatmul<0><<<dim3(BDIM / 64), dim3(256), 0, stream>>>(xr, xi, d_out);
    } else {
        cmatmul<1><<<dim3(BDIM / 64), dim3(256), 0, stream>>>(xr, xi, d_out);
    }
}

// Round 5
// 121.458 us; speedup vs baseline: 5.5219x; 1.0854x over previous
//
#include <hip/hip_runtime.h>
#include <hip/hip_bf16.h>

#define NDIM 128
#define BDIM 131072
#define NMZI 8128                       // 128*127/2
#define NCHUNK 8
#define CSTEP (NMZI / NCHUNK)           // 1016 steps per chunk
#define NJG 8                           // j-groups per block (scan groups)
#define NCOL 32                         // columns per block
#define NLOC 16                         // max local scan length
static constexpr float CC = 0.70710678118654752440f;  // sqrt(0.5)

typedef __attribute__((ext_vector_type(8))) short bf16x8;
typedef __attribute__((ext_vector_type(4))) float f32x4;

// Static device scratch (d_ws size unknown -> don't touch it)
__device__ __align__(16) float2         g_V[NCHUNK * NDIM * NDIM];  // chunk partial unitaries
__device__ __align__(16) float2         g_W[4 * NDIM * NDIM];       // compose level 1
__device__ __align__(16) float2         g_Y[2 * NDIM * NDIM];       // compose level 2
// Packed K=256 table for real-output GEMM: kg2<16 -> Ur[k=kg2*8+e][n]; kg2>=16 -> -Ui
__device__ __align__(16) unsigned short g_TB[32 * NDIM * 8];        // 64 KB
// Separate tables for the (unlikely) complex-interleaved output mode
__device__ __align__(16) unsigned short g_Ur[16 * NDIM * 8];
__device__ __align__(16) unsigned short g_Ui[16 * NDIM * 8];

__device__ inline unsigned short f2bf(float f) {
    union { __hip_bfloat16 h; unsigned short u; } cv;
    cv.h = __float2bfloat16(f);
    return cv.u;
}

// ---------------- K2: build chunk partial unitaries (affine-scan) ----------------
// grid (4 col-slabs, NCHUNK) x 256 threads = (8 j-groups x 32 columns).
// Phases computed in-kernel (phase_prep fused). Within a sweep segment:
// t_j = e_phi*U[j] independent; ri_j = C*ri_{j-1} + C*t_j is an affine
// recurrence -> blocked scan: per-group serial composite in regs, cross-
// group exclusive prefix via LDS, parallel finish.
__global__ __launch_bounds__(256) void build_scan(const float* __restrict__ mzi) {
    __shared__ float2 Usm[NDIM][NCOL];        // 32 KB
    __shared__ float4 phs[CSTEP];             // 16.25 KB
    __shared__ float4 comp[NJG][NCOL];        // 4 KB
    const int tid   = threadIdx.x;
    const int c     = tid & 31;
    const int g     = tid >> 5;
    const int col0  = blockIdx.x * NCOL;
    const int chunk = blockIdx.y;
    const int s0 = chunk * CSTEP, s1 = s0 + CSTEP;

    // V0 = identity slab
    for (int k = g; k < NDIM; k += NJG)
        Usm[k][c] = make_float2((k == col0 + c) ? 1.f : 0.f, 0.f);
    // compute this chunk's phases (fused phase_prep)
    const float2* mzp = (const float2*)mzi;   // (theta, phi) pairs
    for (int t = tid; t < CSTEP; t += 256) {
        const float2 mz = mzp[s0 + t];
        float sp, cp, st, ct;
        sincosf(mz.y, &sp, &cp);              // phi
        sincosf(mz.x, &st, &ct);              // theta
        phs[t] = make_float4(cp, sp, CC * ct, CC * st);
    }
    __syncthreads();

    // locate first sweep of this chunk
    int i = 0, base = 0;
    while (base + (NDIM - 1 - i) <= s0) { base += NDIM - 1 - i; ++i; }

    int s = s0;
    while (s < s1) {
        const int cnt  = NDIM - 1 - i;
        const int jA   = i + 1 + (s - base);          // first row j this segment
        const int L    = min(s1, base + cnt) - s;     // segment length
        const int nloc = (L + NJG - 1) >> 3;
        const int myBeg = g * nloc;
        const int myN   = max(0, min(nloc, L - myBeg));
        const int pbase = s - s0;

        const float2 r0 = Usm[i][c];                  // read BEFORE barrier

        // pass 1: t_j + local affine composite (A, B): r' = A*r + B
        float2 treg[NLOC];
        float2 qth[NLOC];
        float  A = 1.f;
        float2 Bc = make_float2(0.f, 0.f);
        #pragma unroll
        for (int kk = 0; kk < NLOC; ++kk) {
            if (kk < myN) {
                const int off = myBeg + kk;
                const float4 q  = phs[pbase + off];
                const float2 rj = Usm[jA + off][c];
                const float tr = fmaf(q.x, rj.x, -q.y * rj.y);
                const float ti = fmaf(q.x, rj.y,  q.y * rj.x);
                treg[kk] = make_float2(tr, ti);
                qth[kk]  = make_float2(q.z, q.w);
                Bc.x = CC * (Bc.x + tr);
                Bc.y = CC * (Bc.y + ti);
                A *= CC;
            }
        }
        comp[g][c] = make_float4(A, Bc.x, Bc.y, 0.f);
        __syncthreads();

        // exclusive prefix over groups < g, applied to r0
        float2 r = r0;
        for (int h = 0; h < g; ++h) {
            const float4 cm = comp[h][c];
            r.x = fmaf(cm.x, r.x, cm.y);
            r.y = fmaf(cm.x, r.y, cm.z);
        }

        // pass 2: new_j = C*e_th*(ri_{j-1} - t_j); advance r
        #pragma unroll
        for (int kk = 0; kk < NLOC; ++kk) {
            if (kk < myN) {
                const float2 t = treg[kk];
                const float2 q = qth[kk];
                const float dr = r.x - t.x, di = r.y - t.y;
                const float njx = fmaf(q.x, dr, -q.y * di);
                const float njy = fmaf(q.x, di,  q.y * dr);
                Usm[jA + myBeg + kk][c] = make_float2(njx, njy);
                r.x = CC * (r.x + t.x);
                r.y = CC * (r.y + t.y);
            }
        }
        if (myN > 0 && (myBeg + myN == L))
            Usm[i][c] = r;
        __syncthreads();

        s += L;
        if (s == base + cnt) { base += cnt; ++i; }
    }

    float2* Vp = g_V + chunk * NDIM * NDIM;
    for (int k = g; k < NDIM; k += NJG)
        Vp[k * NDIM + col0 + c] = Usm[k][c];
}

// ---------------- K3: compose tree level ----------------
__global__ __launch_bounds__(128) void compose(int level) {
    const int p = blockIdx.y, n = blockIdx.x, m = threadIdx.x;
    const float2* A; const float2* B; float2* Cout;
    if (level == 0) {
        A = g_V + (2 * p + 1) * NDIM * NDIM;
        B = g_V + (2 * p) * NDIM * NDIM;
        Cout = g_W + p * NDIM * NDIM;
    } else {
        A = g_W + (2 * p + 1) * NDIM * NDIM;
        B = g_W + (2 * p) * NDIM * NDIM;
        Cout = g_Y + p * NDIM * NDIM;
    }
    __shared__ float2 arow[NDIM];
    arow[m] = A[n * NDIM + m];
    __syncthreads();
    float cr = 0.f, ci = 0.f;
    #pragma unroll 8
    for (int k = 0; k < NDIM; ++k) {
        const float2 b = B[k * NDIM + m];
        const float2 a = arow[k];
        cr = fmaf(a.x, b.x, fmaf(-a.y, b.y, cr));
        ci = fmaf(a.x, b.y, fmaf( a.y, b.x, ci));
    }
    Cout[n * NDIM + m] = make_float2(cr, ci);
}

// ---------------- K4: final compose U = Y1*Y0, diag, emit packed bf16 ----------------
__global__ __launch_bounds__(128) void compose_final(const float* __restrict__ oph) {
    const int n = blockIdx.x, m = threadIdx.x;
    const float2* A = g_Y + NDIM * NDIM;   // Y1 (left)
    const float2* B = g_Y;                 // Y0 (right)
    __shared__ float2 arow[NDIM];
    arow[m] = A[n * NDIM + m];
    __syncthreads();
    float cr = 0.f, ci = 0.f;
    #pragma unroll 8
    for (int k = 0; k < NDIM; ++k) {
        const float2 b = B[k * NDIM + m];
        const float2 a = arow[k];
        cr = fmaf(a.x, b.x, fmaf(-a.y, b.y, cr));
        ci = fmaf(a.x, b.y, fmaf( a.y, b.x, ci));
    }
    float ds, dc;
    sincosf(oph[n], &ds, &dc);
    const float vr = fmaf(cr, dc, -ci * ds);
    const float vi = fmaf(cr, ds,  ci * dc);
    const int kg = m >> 3, e = m & 7;
    // packed real-GEMM table: [Ur | -Ui], K=256
    g_TB[(kg * NDIM + n) * 8 + e]            = f2bf(vr);
    g_TB[((16 + kg) * NDIM + n) * 8 + e]     = f2bf(-vi);
    // legacy split tables (complex-output mode)
    g_Ur[(kg * NDIM + n) * 8 + e] = f2bf(vr);
    g_Ui[(kg * NDIM + n) * 8 + e] = f2bf(vi);
}

// ---------------- K5a: real-output GEMM (out_size == B*N, f32 real part) ----------------
// 512 blocks x 256 threads (4 waves), 4 tiles of 64 b-rows per block.
// Packed table [Ur | -Ui] staged in LDS (64 KB). MFMA operand-swapped:
// A = table (rows = n), B = x (cols = b)  =>  D rows = n, cols = b, so each
// lane's 4 D regs are 4 consecutive n of one b-row -> single 16B store.
__global__ __launch_bounds__(256, 2) void cmatmul0(const float* __restrict__ xr,
                                                   const float* __restrict__ xi,
                                                   float* __restrict__ out) {
    __shared__ bf16x8 smT[32 * NDIM];     // 64 KB
    const int tid  = threadIdx.x;
    const int lane = tid & 63;
    const int w    = tid >> 6;
    const int r15  = lane & 15;
    const int kg4  = lane >> 4;
    const int rbase = blockIdx.x * 256 + w * 16 + r15;   // this wave-lane's b-row, tile 0

    // tile-0 x loads (issue before staging so they overlap)
    float4 bufA[16], bufB[16];
    {
        const float* xrp = xr + (size_t)rbase * NDIM;
        const float* xip = xi + (size_t)rbase * NDIM;
        #pragma unroll
        for (int kc = 0; kc < 4; ++kc) {
            const int k0 = kc * 32 + kg4 * 8;
            bufA[kc * 2]     = *(const float4*)(xrp + k0);
            bufA[kc * 2 + 1] = *(const float4*)(xrp + k0 + 4);
            bufA[8 + kc * 2]     = *(const float4*)(xip + k0);
            bufA[8 + kc * 2 + 1] = *(const float4*)(xip + k0 + 4);
        }
    }
    // stage packed table into LDS (coalesced 1KB/wave/iter)
    const bf16x8* gT = (const bf16x8*)g_TB;
    for (int t = tid; t < 32 * NDIM; t += 256) smT[t] = gT[t];
    __syncthreads();

    #pragma unroll
    for (int t = 0; t < 4; ++t) {
        float4* cur = (t & 1) ? bufB : bufA;
        float4* nxt = (t & 1) ? bufA : bufB;
        // issue next tile's loads (fill nxt; completes under this tile's MFMAs)
        if (t < 3) {
            const int rn = rbase + (t + 1) * 64;
            const float* xrp = xr + (size_t)rn * NDIM;
            const float* xip = xi + (size_t)rn * NDIM;
            #pragma unroll
            for (int kc = 0; kc < 4; ++kc) {
                const int k0 = kc * 32 + kg4 * 8;
                nxt[kc * 2]     = *(const float4*)(xrp + k0);
                nxt[kc * 2 + 1] = *(const float4*)(xrp + k0 + 4);
                nxt[8 + kc * 2]     = *(const float4*)(xip + k0);
                nxt[8 + kc * 2 + 1] = *(const float4*)(xip + k0 + 4);
            }
        }
        // convert current tile to bf16 B-fragments (K=256: xr then xi)
        bf16x8 fx[8];
        #pragma unroll
        for (int kc2 = 0; kc2 < 8; ++kc2) {
            const float4 lo = cur[kc2 * 2];
            const float4 hi = cur[kc2 * 2 + 1];
            bf16x8 v;
            v[0] = (short)f2bf(lo.x); v[1] = (short)f2bf(lo.y);
            v[2] = (short)f2bf(lo.z); v[3] = (short)f2bf(lo.w);
            v[4] = (short)f2bf(hi.x); v[5] = (short)f2bf(hi.y);
            v[6] = (short)f2bf(hi.z); v[7] = (short)f2bf(hi.w);
            fx[kc2] = v;
        }
        const size_t orow = (size_t)(rbase + t * 64) * NDIM;
        #pragma unroll
        for (int nt = 0; nt < 8; ++nt) {
            f32x4 a0 = {0.f, 0.f, 0.f, 0.f};
            f32x4 a1 = {0.f, 0.f, 0.f, 0.f};
            #pragma unroll
            for (int kc2 = 0; kc2 < 4; ++kc2) {
                const bf16x8 tf = smT[(kc2 * 4 + kg4) * NDIM + nt * 16 + r15];
                a0 = __builtin_amdgcn_mfma_f32_16x16x32_bf16(tf, fx[kc2], a0, 0, 0, 0);
            }
            #pragma unroll
            for (int kc2 = 4; kc2 < 8; ++kc2) {
                const bf16x8 tf = smT[(kc2 * 4 + kg4) * NDIM + nt * 16 + r15];
                a1 = __builtin_amdgcn_mfma_f32_16x16x32_bf16(tf, fx[kc2], a1, 0, 0, 0);
            }
            const f32x4 sum = a0 + a1;
            *(float4*)(out + orow + nt * 16 + kg4 * 4) =
                make_float4(sum[0], sum[1], sum[2], sum[3]);
        }
    }
}

// ---------------- K5b: complex-output fallback (bf16 re,im pairs) ----------------
__global__ __launch_bounds__(256) void cmatmul1(const float* __restrict__ xr,
                                                const float* __restrict__ xi,
                                                ushort2* __restrict__ outp) {
    const int lane  = threadIdx.x & 63;
    const int w     = threadIdx.x >> 6;
    const int btile = blockIdx.x * 64 + w * 16;
    const int r15   = lane & 15;
    const int kg4   = lane >> 4;
    const int bload = btile + r15;

    const bf16x8* Ur = (const bf16x8*)g_Ur;
    const bf16x8* Ui = (const bf16x8*)g_Ui;
    const float* xrp = xr + (size_t)bload * NDIM;
    const float* xip = xi + (size_t)bload * NDIM;

    bf16x8 ar[4], ai[4], ain[4];
    #pragma unroll
    for (int kc = 0; kc < 4; ++kc) {
        const int k0 = kc * 32 + kg4 * 8;
        float4 rlo = *(const float4*)(xrp + k0);
        float4 rhi = *(const float4*)(xrp + k0 + 4);
        float4 ilo = *(const float4*)(xip + k0);
        float4 ihi = *(const float4*)(xip + k0 + 4);
        bf16x8 vr, vi, vn;
        vr[0] = (short)f2bf(rlo.x); vr[1] = (short)f2bf(rlo.y);
        vr[2] = (short)f2bf(rlo.z); vr[3] = (short)f2bf(rlo.w);
        vr[4] = (short)f2bf(rhi.x); vr[5] = (short)f2bf(rhi.y);
        vr[6] = (short)f2bf(rhi.z); vr[7] = (short)f2bf(rhi.w);
        vi[0] = (short)f2bf(ilo.x); vi[1] = (short)f2bf(ilo.y);
        vi[2] = (short)f2bf(ilo.z); vi[3] = (short)f2bf(ilo.w);
        vi[4] = (short)f2bf(ihi.x); vi[5] = (short)f2bf(ihi.y);
        vi[6] = (short)f2bf(ihi.z); vi[7] = (short)f2bf(ihi.w);
        #pragma unroll
        for (int e = 0; e < 8; ++e) vn[e] = (short)(vi[e] ^ 0x8000);
        ar[kc] = vr; ai[kc] = vi; ain[kc] = vn;
    }

    #pragma unroll
    for (int nt = 0; nt < 8; ++nt) {
        f32x4 accR = {0.f, 0.f, 0.f, 0.f};
        f32x4 accI = {0.f, 0.f, 0.f, 0.f};
        #pragma unroll
        for (int kc = 0; kc < 4; ++kc) {
            const int kg = kc * 4 + kg4;
            bf16x8 br = Ur[kg * NDIM + nt * 16 + r15];
            bf16x8 bi = Ui[kg * NDIM + nt * 16 + r15];
            accR = __builtin_amdgcn_mfma_f32_16x16x32_bf16(ar[kc],  br, accR, 0, 0, 0);
            accR = __builtin_amdgcn_mfma_f32_16x16x32_bf16(ain[kc], bi, accR, 0, 0, 0);
            accI = __builtin_amdgcn_mfma_f32_16x16x32_bf16(ar[kc],  bi, accI, 0, 0, 0);
            accI = __builtin_amdgcn_mfma_f32_16x16x32_bf16(ai[kc],  br, accI, 0, 0, 0);
        }
        const int n    = nt * 16 + r15;
        const int brow = btile + kg4 * 4;
        #pragma unroll
        for (int r = 0; r < 4; ++r)
            outp[(size_t)(brow + r) * NDIM + n] = make_ushort2(f2bf(accR[r]), f2bf(accI[r]));
    }
}

extern "C" void kernel_launch(void* const* d_in, const int* in_sizes, int n_in,
                              void* d_out, int out_size, void* d_ws, size_t ws_size,
                              hipStream_t stream) {
    const float* xr  = (const float*)d_in[0];
    const float* xi  = (const float*)d_in[1];
    const float* mzi = (const float*)d_in[2];
    const float* oph = (const float*)d_in[3];

    build_scan<<<dim3(4, NCHUNK), dim3(256), 0, stream>>>(mzi);
    compose<<<dim3(NDIM, 4), dim3(128), 0, stream>>>(0);
    compose<<<dim3(NDIM, 2), dim3(128), 0, stream>>>(1);
    compose_final<<<dim3(NDIM), dim3(128), 0, stream>>>(oph);
    if (out_size == BDIM * NDIM) {
        cmatmul0<<<dim3(512), dim3(256), 0, stream>>>(xr, xi, (float*)d_out);
    } else {
        cmatmul1<<<dim3(BDIM / 64), dim3(256), 0, stream>>>(xr, xi, (ushort2*)d_out);
    }
}